// Round 8
// baseline (54.346 us; speedup 1.0000x reference)
//
#include <hip/hip_runtime.h>
#include <hip/hip_fp16.h>

// Problem constants (fixed shapes from setup_inputs)
constexpr int KK = 3;
constexpr int K2 = 9;          // KK*KK
constexpr int PADC = 1;        // (KK-1)/2
constexpr float DECAY = 4.0f;
constexpr float RELT = 0.3f;
constexpr float EPSV = 1e-8f;
constexpr int H = 480;
constexpr int W = 640;
constexpr int HW = H * W;

typedef float f32x4 __attribute__((ext_vector_type(4)));   // native vector: ok for nontemporal builtins

// Tiling: each block produces a 16x64 tile; 256 threads x 4 px (float4 I/O).
constexpr int TH = 16;
constexpr int TW = 64;
constexpr int PADT = 8;              // apron: N(0,1) offsets + kernel +-1 stay within +-8 in practice
constexpr int LR = TH + 2 * PADT;    // 32 staged rows
constexpr int LC = TW + 2 * PADT;    // 80 staged cols (valid)

// Packed-f16 pair tile: two parity planes of horizontal __half2 pairs.
// plane p, row y, pair xp holds (tex[y][2*xp+p], tex[y][2*xp+p+1]).
// A bilinear tap = 2 ds_read_b32 (one per row), any x0 parity, no alignment issue.
constexpr int NP = 40;               // pairs per row (uniform for both planes)
constexpr int SP = NP + 1;           // 41: odd row stride de-phases banks
constexpr int PLANE = LR * SP;       // 1312 half2 slots
constexpr int NSLOT = 2 * LR * NP;   // 2560 = 10 * 256 exactly

// Global-path bilinear corner fetch with zero padding (always-correct fallback, full f32).
__device__ __forceinline__ float dsample(const float* __restrict__ img, int iy, int ix) {
    bool valid = (iy >= 0) & (iy < H) & (ix >= 0) & (ix < W);
    int iyc = min(max(iy, 0), H - 1);
    int ixc = min(max(ix, 0), W - 1);
    float v = img[iyc * W + ixc];
    return valid ? v : 0.0f;
}

// One bilinear tap for 4 consecutive pixels; single fast/slow branch per tap.
__device__ __forceinline__ void tap4(const __half2* __restrict__ tile,
                                     const float* __restrict__ dimg,
                                     int by0, int bx0, int r, int col,
                                     f32x4 oy, f32x4 ox, int ky, int kx,
                                     float* s4) {
    int y0[4], x0[4];
    float wy[4], wx[4];
    bool fast = true;
#pragma unroll
    for (int j = 0; j < 4; ++j) {
        float pyt = oy[j] + (float)(r + PADT + ky);
        float pxt = ox[j] + (float)(col + j + PADT + kx);
        float y0f = floorf(pyt);
        float x0f = floorf(pxt);
        wy[j] = pyt - y0f;
        wx[j] = pxt - x0f;
        y0[j] = (int)y0f;
        x0[j] = (int)x0f;
        fast &= ((unsigned)y0[j] < (unsigned)(LR - 1)) & ((unsigned)x0[j] < (unsigned)(LC - 1));
    }
    if (fast) {
        // zeros for out-of-image texels are already staged in the tile
#pragma unroll
        for (int j = 0; j < 4; ++j) {
            int p  = x0[j] & 1;
            int a  = p * PLANE + y0[j] * SP + (x0[j] >> 1);
            float2 f0 = __half22float2(tile[a]);        // (v00, v01)
            float2 f1 = __half22float2(tile[a + SP]);   // (v10, v11)
            float wy1 = 1.0f - wy[j];
            float wx1 = 1.0f - wx[j];
            s4[j] = f0.x * wy1 * wx1 + f0.y * wy1 * wx[j] + f1.x * wy[j] * wx1 + f1.y * wy[j] * wx[j];
        }
    } else {
        // rare: sample outside the apron -> fully general global path
#pragma unroll
        for (int j = 0; j < 4; ++j) {
            int gy = y0[j] + by0 - PADT;
            int gx = x0[j] + bx0 - PADT;
            float v00 = dsample(dimg, gy, gx);
            float v01 = dsample(dimg, gy, gx + 1);
            float v10 = dsample(dimg, gy + 1, gx);
            float v11 = dsample(dimg, gy + 1, gx + 1);
            float wy1 = 1.0f - wy[j];
            float wx1 = 1.0f - wx[j];
            s4[j] = v00 * wy1 * wx1 + v01 * wy1 * wx[j] + v10 * wy[j] * wx1 + v11 * wy[j] * wx[j];
        }
    }
}

__global__ __launch_bounds__(256) void affinity_kernel(
    const float* __restrict__ depth,    // [B,1,H,W]
    const float* __restrict__ offset,   // [B,2*K2,H,W]
    float* __restrict__ out)            // [B,K2,H,W]
{
    const int bx0 = blockIdx.x * TW;
    const int by0 = blockIdx.y * TH;
    const int b   = blockIdx.z;
    const int t   = threadIdx.x;

    __shared__ __half2 tile[2 * PLANE];

    const float* __restrict__ dimg = depth + (size_t)b * HW;

    const int col = (t & 15) * 4;        // 4 consecutive x per thread (16B aligned)
    const int r   = t >> 4;              // 0..15
    const int y   = by0 + r;
    const int x   = bx0 + col;

    const size_t obase = ((size_t)b * 2 * K2) * HW + (size_t)y * W + x;
    const float* __restrict__ offp = offset + obase;

    // Channel order: center (k=4) first so thresholds are ready before the rest.
    constexpr int ORD[K2] = {4, 0, 1, 2, 3, 5, 6, 7, 8};

    // Issue the first channel's loads before staging: latency hides under staging+barrier.
    f32x4 oyc = *reinterpret_cast<const f32x4*>(offp + (size_t)(2 * ORD[0]) * HW);
    f32x4 oxc = *reinterpret_cast<const f32x4*>(offp + (size_t)(2 * ORD[0] + 1) * HW);

    // Stage the depth apron as packed f16 pairs, zero padding baked in.
    // slot s -> plane pl, row rr, pair xp. Depth reads are L1/L2-hot (tiny image).
#pragma unroll
    for (int i = 0; i < NSLOT / 256; ++i) {
        int s  = t + i * 256;
        int pl = s / (LR * NP);              // constant divisors
        int rem = s - pl * (LR * NP);
        int rr = rem / NP;
        int xp = rem - rr * NP;
        int gy = by0 - PADT + rr;
        int gx = bx0 - PADT + 2 * xp + pl;
        float va = 0.0f, vb = 0.0f;
        bool yok = (unsigned)gy < (unsigned)H;
        int rowb = gy * W;
        if (yok & ((unsigned)gx < (unsigned)W))       va = dimg[rowb + gx];
        if (yok & ((unsigned)(gx + 1) < (unsigned)W)) vb = dimg[rowb + gx + 1];
        tile[pl * PLANE + rr * SP + xp] = __floats2half2_rn(va, vb);
    }
    __syncthreads();

    float* __restrict__ outp = out + ((size_t)b * K2) * HW + (size_t)y * W + x;

    float c4[4], thr[4], cr[4];

    // Rolling 1-deep prefetch: issue k+1's offset loads before computing k.
#pragma unroll
    for (int i = 0; i < K2; ++i) {
        const int k = ORD[i];
        f32x4 oyn, oxn;
        if (i + 1 < K2) {
            oyn = *reinterpret_cast<const f32x4*>(offp + (size_t)(2 * ORD[i + 1]) * HW);
            oxn = *reinterpret_cast<const f32x4*>(offp + (size_t)(2 * ORD[i + 1] + 1) * HW);
        }

        float s4[4];
        tap4(tile, dimg, by0, bx0, r, col, oyc, oxc, k / KK - PADC, k % KK - PADC, s4);

        if (i == 0) {
            // center channel: defines thresholds; its own output is identically 1.0
#pragma unroll
            for (int j = 0; j < 4; ++j) {
                c4[j]  = s4[j];
                thr[j] = RELT * (s4[j] + EPSV);  // diff/(c+eps)<=0.3 <=> diff<=0.3*(c+eps), c>=0
                cr[j]  = RELT * s4[j];
            }
            f32x4 ones = {1.0f, 1.0f, 1.0f, 1.0f};
            __builtin_nontemporal_store(ones, reinterpret_cast<f32x4*>(outp + (size_t)4 * HW));
        } else {
            f32x4 vals;
#pragma unroll
            for (int j = 0; j < 4; ++j) {
                float diff = fabsf(s4[j] - c4[j]);
                float aff = __expf(-DECAY * (diff - cr[j]));
                vals[j] = (diff <= thr[j]) ? 1.0f : aff;
            }
            __builtin_nontemporal_store(vals, reinterpret_cast<f32x4*>(outp + (size_t)k * HW));
        }
        oyc = oyn;
        oxc = oxn;
    }
}

extern "C" void kernel_launch(void* const* d_in, const int* in_sizes, int n_in,
                              void* d_out, int out_size, void* d_ws, size_t ws_size,
                              hipStream_t stream) {
    const float* depth = (const float*)d_in[0];
    const float* offset = (const float*)d_in[1];
    float* out = (float*)d_out;

    int B = in_sizes[0] / HW;          // depth is [B,1,H,W]
    dim3 grid(W / TW, H / TH, B);      // 10 x 30 x B
    affinity_kernel<<<grid, 256, 0, stream>>>(depth, offset, out);
}

// Round 9
// 50.843 us; speedup vs baseline: 1.0689x; 1.0689x over previous
//
#include <hip/hip_runtime.h>

// Problem constants (fixed shapes from setup_inputs)
constexpr int KK = 3;
constexpr int K2 = 9;          // KK*KK
constexpr int PADC = 1;        // (KK-1)/2
constexpr float DECAY = 4.0f;
constexpr float RELT = 0.3f;
constexpr float EPSV = 1e-8f;
constexpr int H = 480;
constexpr int W = 640;
constexpr int HW = H * W;

typedef float f32x2 __attribute__((ext_vector_type(2)));   // native vectors: ok for nontemporal builtins

// Tiling: each block produces an 8x64 tile; 256 threads x 2 px (f32x2 I/O).
constexpr int TH = 8;
constexpr int TW = 64;
constexpr int PADT = 8;              // apron: N(0,1) offsets + kernel +-1 stay within +-8 in practice
constexpr int LR = TH + 2 * PADT;    // 24 staged rows
constexpr int LC = TW + 2 * PADT;    // 80 staged cols (valid)
constexpr int LSTRIDE = LC + 1;      // 81: odd stride de-phases LDS banks across rows
constexpr int NSTAGE = LR * LC;      // 1920

// Global-path bilinear corner fetch with zero padding (always-correct fallback).
__device__ __forceinline__ float dsample(const float* __restrict__ img, int iy, int ix) {
    bool valid = (iy >= 0) & (iy < H) & (ix >= 0) & (ix < W);
    int iyc = min(max(iy, 0), H - 1);
    int ixc = min(max(ix, 0), W - 1);
    float v = img[iyc * W + ixc];
    return valid ? v : 0.0f;
}

// One bilinear tap for 2 consecutive pixels; single fast/slow branch per tap.
__device__ __forceinline__ void tap2(const float* __restrict__ tile,
                                     const float* __restrict__ dimg,
                                     int by0, int bx0, int r, int col,
                                     f32x2 oy, f32x2 ox, int ky, int kx,
                                     float* s2) {
    int y0[2], x0[2];
    float wy[2], wx[2];
    bool fast = true;
#pragma unroll
    for (int j = 0; j < 2; ++j) {
        float pyt = oy[j] + (float)(r + PADT + ky);
        float pxt = ox[j] + (float)(col + j + PADT + kx);
        float y0f = floorf(pyt);
        float x0f = floorf(pxt);
        wy[j] = pyt - y0f;
        wx[j] = pxt - x0f;
        y0[j] = (int)y0f;
        x0[j] = (int)x0f;
        fast &= ((unsigned)y0[j] < (unsigned)(LR - 1)) & ((unsigned)x0[j] < (unsigned)(LC - 1));
    }
    if (fast) {
        // zeros for out-of-image texels are already staged in the tile
#pragma unroll
        for (int j = 0; j < 2; ++j) {
            int a = y0[j] * LSTRIDE + x0[j];
            float v00 = tile[a];
            float v01 = tile[a + 1];
            float v10 = tile[a + LSTRIDE];
            float v11 = tile[a + LSTRIDE + 1];
            float wy1 = 1.0f - wy[j];
            float wx1 = 1.0f - wx[j];
            s2[j] = v00 * wy1 * wx1 + v01 * wy1 * wx[j] + v10 * wy[j] * wx1 + v11 * wy[j] * wx[j];
        }
    } else {
        // rare: sample outside the apron -> fully general global path
#pragma unroll
        for (int j = 0; j < 2; ++j) {
            int gy = y0[j] + by0 - PADT;
            int gx = x0[j] + bx0 - PADT;
            float v00 = dsample(dimg, gy, gx);
            float v01 = dsample(dimg, gy, gx + 1);
            float v10 = dsample(dimg, gy + 1, gx);
            float v11 = dsample(dimg, gy + 1, gx + 1);
            float wy1 = 1.0f - wy[j];
            float wx1 = 1.0f - wx[j];
            s2[j] = v00 * wy1 * wx1 + v01 * wy1 * wx[j] + v10 * wy[j] * wx1 + v11 * wy[j] * wx[j];
        }
    }
}

__global__ __launch_bounds__(256) void affinity_kernel(
    const float* __restrict__ depth,    // [B,1,H,W]
    const float* __restrict__ offset,   // [B,2*K2,H,W]
    float* __restrict__ out)            // [B,K2,H,W]
{
    const int bx0 = blockIdx.x * TW;
    const int by0 = blockIdx.y * TH;
    const int b   = blockIdx.z;
    const int t   = threadIdx.x;

    __shared__ float tile[LR * LSTRIDE];

    const float* __restrict__ dimg = depth + (size_t)b * HW;

    const int col = (t & 31) * 2;        // 2 consecutive x per thread (8B aligned)
    const int r   = t >> 5;              // 0..7
    const int y   = by0 + r;
    const int x   = bx0 + col;

    const size_t obase = ((size_t)b * 2 * K2) * HW + (size_t)y * W + x;
    const float* __restrict__ offp = offset + obase;

    // Channel order: center (k=4) first so thresholds are ready before the rest.
    constexpr int ORD[K2] = {4, 0, 1, 2, 3, 5, 6, 7, 8};

    // Issue the first channel's loads before staging: latency hides under staging+barrier.
    f32x2 oyc = *reinterpret_cast<const f32x2*>(offp + (size_t)(2 * ORD[0]) * HW);
    f32x2 oxc = *reinterpret_cast<const f32x2*>(offp + (size_t)(2 * ORD[0] + 1) * HW);

    // Stage depth apron into LDS with zero padding baked in (coalesced).
#pragma unroll
    for (int i = 0; i < (NSTAGE + 255) / 256; ++i) {
        int idx = t + i * 256;
        if (idx < NSTAGE) {
            int rr = idx / LC;           // constant divisor
            int cc = idx - rr * LC;
            int yi = by0 - PADT + rr;
            int xi = bx0 - PADT + cc;
            float v = 0.0f;
            if ((unsigned)yi < (unsigned)H && (unsigned)xi < (unsigned)W)
                v = dimg[yi * W + xi];
            tile[rr * LSTRIDE + cc] = v;
        }
    }
    __syncthreads();

    float* __restrict__ outp = out + ((size_t)b * K2) * HW + (size_t)y * W + x;

    float c2[2], thr[2], cr[2];

    // Rolling 1-deep prefetch: issue k+1's offset loads before computing k.
#pragma unroll
    for (int i = 0; i < K2; ++i) {
        const int k = ORD[i];
        f32x2 oyn, oxn;
        if (i + 1 < K2) {
            oyn = *reinterpret_cast<const f32x2*>(offp + (size_t)(2 * ORD[i + 1]) * HW);
            oxn = *reinterpret_cast<const f32x2*>(offp + (size_t)(2 * ORD[i + 1] + 1) * HW);
        }

        float s2[2];
        tap2(tile, dimg, by0, bx0, r, col, oyc, oxc, k / KK - PADC, k % KK - PADC, s2);

        if (i == 0) {
            // center channel: defines thresholds; its own output is identically 1.0
#pragma unroll
            for (int j = 0; j < 2; ++j) {
                c2[j]  = s2[j];
                thr[j] = RELT * (s2[j] + EPSV);  // diff/(c+eps)<=0.3 <=> diff<=0.3*(c+eps), c>=0
                cr[j]  = RELT * s2[j];
            }
            f32x2 ones = {1.0f, 1.0f};
            __builtin_nontemporal_store(ones, reinterpret_cast<f32x2*>(outp + (size_t)4 * HW));
        } else {
            f32x2 vals;
#pragma unroll
            for (int j = 0; j < 2; ++j) {
                float diff = fabsf(s2[j] - c2[j]);
                float aff = __expf(-DECAY * (diff - cr[j]));
                vals[j] = (diff <= thr[j]) ? 1.0f : aff;
            }
            __builtin_nontemporal_store(vals, reinterpret_cast<f32x2*>(outp + (size_t)k * HW));
        }
        oyc = oyn;
        oxc = oxn;
    }
}

extern "C" void kernel_launch(void* const* d_in, const int* in_sizes, int n_in,
                              void* d_out, int out_size, void* d_ws, size_t ws_size,
                              hipStream_t stream) {
    const float* depth = (const float*)d_in[0];
    const float* offset = (const float*)d_in[1];
    float* out = (float*)d_out;

    int B = in_sizes[0] / HW;          // depth is [B,1,H,W]
    dim3 grid(W / TW, H / TH, B);      // 10 x 60 x B
    affinity_kernel<<<grid, 256, 0, stream>>>(depth, offset, out);
}

// Round 10
// 50.533 us; speedup vs baseline: 1.0755x; 1.0061x over previous
//
#include <hip/hip_runtime.h>

// Problem constants (fixed shapes from setup_inputs)
constexpr int KK = 3;
constexpr int K2 = 9;          // KK*KK
constexpr int PADC = 1;        // (KK-1)/2
constexpr float DECAY = 4.0f;
constexpr float RELT = 0.3f;
constexpr float EPSV = 1e-8f;
constexpr int H = 480;
constexpr int W = 640;
constexpr int HW = H * W;

typedef float f32x4 __attribute__((ext_vector_type(4)));   // native vector: ok for nontemporal builtins

// Tiling: each block produces a 16x64 tile; 256 threads x 4 px (float4 I/O).
constexpr int TH = 16;
constexpr int TW = 64;
constexpr int PADT = 8;              // apron: N(0,1) offsets + kernel +-1 stay within +-8 in practice
constexpr int LR = TH + 2 * PADT;    // 32 staged rows
constexpr int LC = TW + 2 * PADT;    // 80 staged cols (valid)
constexpr int LSTRIDE = LC + 1;      // 81: odd stride de-phases LDS banks across rows
constexpr int NSTAGE = LR * LC;      // 2560 = 10 * 256 exactly

// Global-path bilinear corner fetch with zero padding (always-correct fallback).
__device__ __forceinline__ float dsample(const float* __restrict__ img, int iy, int ix) {
    bool valid = (iy >= 0) & (iy < H) & (ix >= 0) & (ix < W);
    int iyc = min(max(iy, 0), H - 1);
    int ixc = min(max(ix, 0), W - 1);
    float v = img[iyc * W + ixc];
    return valid ? v : 0.0f;
}

// One bilinear tap for 4 consecutive pixels; single fast/slow branch per tap.
// Blend in lerp form: 3 fma + 2 sub per sub-pixel (vs ~13 ops product form).
__device__ __forceinline__ void tap4(const float* __restrict__ tile,
                                     const float* __restrict__ dimg,
                                     int by0, int bx0, int r, int col,
                                     f32x4 oy, f32x4 ox, int ky, int kx,
                                     float* s4) {
    int y0[4], x0[4];
    float wy[4], wx[4];
    bool fast = true;
#pragma unroll
    for (int j = 0; j < 4; ++j) {
        float pyt = oy[j] + (float)(r + PADT + ky);
        float pxt = ox[j] + (float)(col + j + PADT + kx);
        float y0f = floorf(pyt);
        float x0f = floorf(pxt);
        wy[j] = pyt - y0f;
        wx[j] = pxt - x0f;
        y0[j] = (int)y0f;
        x0[j] = (int)x0f;
        fast &= ((unsigned)y0[j] < (unsigned)(LR - 1)) & ((unsigned)x0[j] < (unsigned)(LC - 1));
    }
    if (fast) {
        // zeros for out-of-image texels are already staged in the tile
#pragma unroll
        for (int j = 0; j < 4; ++j) {
            int a = y0[j] * LSTRIDE + x0[j];
            float v00 = tile[a];
            float v01 = tile[a + 1];
            float v10 = tile[a + LSTRIDE];
            float v11 = tile[a + LSTRIDE + 1];
            float h0 = fmaf(wx[j], v01 - v00, v00);
            float h1 = fmaf(wx[j], v11 - v10, v10);
            s4[j] = fmaf(wy[j], h1 - h0, h0);
        }
    } else {
        // rare: sample outside the apron -> fully general global path
#pragma unroll
        for (int j = 0; j < 4; ++j) {
            int gy = y0[j] + by0 - PADT;
            int gx = x0[j] + bx0 - PADT;
            float v00 = dsample(dimg, gy, gx);
            float v01 = dsample(dimg, gy, gx + 1);
            float v10 = dsample(dimg, gy + 1, gx);
            float v11 = dsample(dimg, gy + 1, gx + 1);
            float h0 = fmaf(wx[j], v01 - v00, v00);
            float h1 = fmaf(wx[j], v11 - v10, v10);
            s4[j] = fmaf(wy[j], h1 - h0, h0);
        }
    }
}

__global__ __launch_bounds__(256) void affinity_kernel(
    const float* __restrict__ depth,    // [B,1,H,W]
    const float* __restrict__ offset,   // [B,2*K2,H,W]
    float* __restrict__ out)            // [B,K2,H,W]
{
    const int bx0 = blockIdx.x * TW;
    const int by0 = blockIdx.y * TH;
    const int b   = blockIdx.z;
    const int t   = threadIdx.x;

    __shared__ float tile[LR * LSTRIDE];

    const float* __restrict__ dimg = depth + (size_t)b * HW;

    const int col = (t & 15) * 4;        // 4 consecutive x per thread (16B aligned)
    const int r   = t >> 4;              // 0..15
    const int y   = by0 + r;
    const int x   = bx0 + col;

    const size_t obase = ((size_t)b * 2 * K2) * HW + (size_t)y * W + x;
    const float* __restrict__ offp = offset + obase;

    // Channel order: center (k=4) first so thresholds are ready before the rest.
    constexpr int ORD[K2] = {4, 0, 1, 2, 3, 5, 6, 7, 8};

    // 2-deep rolling prefetch buffer (static indexing: loop is fully unrolled).
    f32x4 oyb[2], oxb[2];
    oyb[0] = *reinterpret_cast<const f32x4*>(offp + (size_t)(2 * ORD[0]) * HW);
    oxb[0] = *reinterpret_cast<const f32x4*>(offp + (size_t)(2 * ORD[0] + 1) * HW);
    oyb[1] = *reinterpret_cast<const f32x4*>(offp + (size_t)(2 * ORD[1]) * HW);
    oxb[1] = *reinterpret_cast<const f32x4*>(offp + (size_t)(2 * ORD[1] + 1) * HW);

    // Stage depth apron into LDS with zero padding baked in (coalesced, exact fit).
    // The two prefetched channels' load latency hides under this + the barrier.
#pragma unroll
    for (int i = 0; i < NSTAGE / 256; ++i) {
        int idx = t + i * 256;
        int rr = idx / LC;               // constant divisor
        int cc = idx - rr * LC;
        int yi = by0 - PADT + rr;
        int xi = bx0 - PADT + cc;
        float v = 0.0f;
        if ((unsigned)yi < (unsigned)H && (unsigned)xi < (unsigned)W)
            v = dimg[yi * W + xi];
        tile[rr * LSTRIDE + cc] = v;
    }
    __syncthreads();

    float* __restrict__ outp = out + ((size_t)b * K2) * HW + (size_t)y * W + x;

    float c4[4], thr[4], cr[4];

#pragma unroll
    for (int i = 0; i < K2; ++i) {
        const int k = ORD[i];
        // Consume slot i&1, then immediately refill it with channel i+2 so two
        // channels' loads are always in flight ahead of the compute.
        f32x4 oyc = oyb[i & 1];
        f32x4 oxc = oxb[i & 1];
        if (i + 2 < K2) {
            oyb[i & 1] = *reinterpret_cast<const f32x4*>(offp + (size_t)(2 * ORD[i + 2]) * HW);
            oxb[i & 1] = *reinterpret_cast<const f32x4*>(offp + (size_t)(2 * ORD[i + 2] + 1) * HW);
        }

        float s4[4];
        tap4(tile, dimg, by0, bx0, r, col, oyc, oxc, k / KK - PADC, k % KK - PADC, s4);

        if (i == 0) {
            // center channel: defines thresholds; its own output is identically 1.0
#pragma unroll
            for (int j = 0; j < 4; ++j) {
                c4[j]  = s4[j];
                thr[j] = RELT * (s4[j] + EPSV);  // diff/(c+eps)<=0.3 <=> diff<=0.3*(c+eps), c>=0
                cr[j]  = RELT * s4[j];
            }
            f32x4 ones = {1.0f, 1.0f, 1.0f, 1.0f};
            __builtin_nontemporal_store(ones, reinterpret_cast<f32x4*>(outp + (size_t)4 * HW));
        } else {
            f32x4 vals;
#pragma unroll
            for (int j = 0; j < 4; ++j) {
                float diff = fabsf(s4[j] - c4[j]);
                float aff = __expf(-DECAY * (diff - cr[j]));
                vals[j] = (diff <= thr[j]) ? 1.0f : aff;
            }
            __builtin_nontemporal_store(vals, reinterpret_cast<f32x4*>(outp + (size_t)k * HW));
        }
    }
}

extern "C" void kernel_launch(void* const* d_in, const int* in_sizes, int n_in,
                              void* d_out, int out_size, void* d_ws, size_t ws_size,
                              hipStream_t stream) {
    const float* depth = (const float*)d_in[0];
    const float* offset = (const float*)d_in[1];
    float* out = (float*)d_out;

    int B = in_sizes[0] / HW;          // depth is [B,1,H,W]
    dim3 grid(W / TW, H / TH, B);      // 10 x 30 x B
    affinity_kernel<<<grid, 256, 0, stream>>>(depth, offset, out);
}